// Round 1
// baseline (359.539 us; speedup 1.0000x reference)
//
#include <hip/hip_runtime.h>
#include <stdint.h>

#define N_ROWS 65536
#define K_CODES 1024
#define D 64
#define SPLIT 4
#define KPT (K_CODES / SPLIT)   // 256 codes scanned per thread
#define KT 128                  // codes per LDS tile (32 KiB)
#define OUT_ELEMS 4194304
#define LOSS_SCALE (1.25f / 4194304.0f)

// ||e_k||^2 for all codes
__global__ __launch_bounds__(256) void e2_kernel(const float* __restrict__ emb,
                                                 float* __restrict__ e2) {
    int k = blockIdx.x * 256 + threadIdx.x;
    if (k >= K_CODES) return;
    const float4* e4 = (const float4*)emb;
    float s = 0.f;
#pragma unroll
    for (int i = 0; i < 16; i++) {
        float4 v = e4[k * 16 + i];
        s += v.x * v.x + v.y * v.y + v.z * v.z + v.w * v.w;
    }
    e2[k] = s;
}

// Split-K distance scan: block = (row-tile of 256) x (one of 4 K-splits).
// Each thread holds its z-row (64 f32 in regs), scans 256 codes staged in LDS.
// Emits packed key: monotone-encoded dist in high 32b, code index in low 32b,
// so u64-min == (min dist, then smallest k) — numpy argmin tie semantics.
__global__ __launch_bounds__(256) void dist_kernel(const float* __restrict__ z,
                                                   const float* __restrict__ emb,
                                                   const float* __restrict__ e2,
                                                   unsigned long long* __restrict__ keys) {
    const int s = blockIdx.x & (SPLIT - 1);
    const int rowtile = blockIdx.x >> 2;
    const int n = rowtile * 256 + threadIdx.x;

    const float4* z4 = (const float4*)(z + (size_t)n * D);
    float4 zr[16];
#pragma unroll
    for (int i = 0; i < 16; i++) zr[i] = z4[i];

    __shared__ float4 se[KT * 16];  // 32 KiB code tile
    __shared__ float se2[KT];

    float bestd = INFINITY;
    int best = 0;
    const int k0base = s * KPT;
    const float4* ef = (const float4*)emb;

    for (int t = 0; t < KPT / KT; t++) {
        int k0 = k0base + t * KT;
        __syncthreads();
#pragma unroll
        for (int j = 0; j < 8; j++)
            se[j * 256 + threadIdx.x] = ef[k0 * 16 + j * 256 + threadIdx.x];
        if (threadIdx.x < KT) se2[threadIdx.x] = e2[k0 + threadIdx.x];
        __syncthreads();
        for (int k = 0; k < KT; k++) {
            float4 a = {0.f, 0.f, 0.f, 0.f};
#pragma unroll
            for (int i = 0; i < 16; i++) {
                float4 e = se[k * 16 + i];  // uniform addr -> LDS broadcast
                a.x += zr[i].x * e.x;
                a.y += zr[i].y * e.y;
                a.z += zr[i].z * e.z;
                a.w += zr[i].w * e.w;
            }
            float dot = (a.x + a.y) + (a.z + a.w);
            float dist = se2[k] - 2.0f * dot;  // ||z||^2 dropped (row-constant)
            if (dist < bestd) { bestd = dist; best = k0 + k; }
        }
    }
    unsigned int db = __float_as_uint(bestd);
    db = (db & 0x80000000u) ? ~db : (db | 0x80000000u);  // monotone float encode
    keys[(size_t)s * N_ROWS + n] = ((unsigned long long)db << 32) | (unsigned int)best;
}

__global__ __launch_bounds__(256) void combine_kernel(const unsigned long long* __restrict__ keys,
                                                      int* __restrict__ idx) {
    int n = blockIdx.x * 256 + threadIdx.x;
    unsigned long long m = keys[n];
#pragma unroll
    for (int s = 1; s < SPLIT; s++) {
        unsigned long long v = keys[(size_t)s * N_ROWS + n];
        m = v < m ? v : m;
    }
    idx[n] = (int)(m & 0xFFFFFFFFu);
}

// Gather codebook rows (coalesced writes), accumulate 1.25 * mean((q - z)^2).
__global__ __launch_bounds__(256) void quant_kernel(const float* __restrict__ z,
                                                    const float* __restrict__ emb,
                                                    const int* __restrict__ idx,
                                                    float* __restrict__ out,
                                                    float* __restrict__ loss) {
    int i = blockIdx.x * 256 + threadIdx.x;  // float4 index
    int n = i >> 4;
    int d4 = i & 15;
    int k = idx[n];  // 16 consecutive threads share n -> cached
    float4 q = ((const float4*)emb)[k * 16 + d4];
    float4 zv = ((const float4*)z)[i];
    ((float4*)out)[i] = q;
    float dx = q.x - zv.x, dy = q.y - zv.y, dz = q.z - zv.z, dw = q.w - zv.w;
    float ssum = dx * dx + dy * dy + dz * dz + dw * dw;
#pragma unroll
    for (int off = 32; off > 0; off >>= 1)
        ssum += __shfl_down(ssum, off, 64);
    __shared__ float ps[4];
    int wave = threadIdx.x >> 6;
    int lane = threadIdx.x & 63;
    if (lane == 0) ps[wave] = ssum;
    __syncthreads();
    if (threadIdx.x == 0) {
        float bs = ps[0] + ps[1] + ps[2] + ps[3];
        atomicAdd(loss, bs * LOSS_SCALE);
    }
}

extern "C" void kernel_launch(void* const* d_in, const int* in_sizes, int n_in,
                              void* d_out, int out_size, void* d_ws, size_t ws_size,
                              hipStream_t stream) {
    const float* z = (const float*)d_in[0];
    const float* emb = (const float*)d_in[1];
    float* out = (float*)d_out;
    float* loss = out + OUT_ELEMS;

    char* ws = (char*)d_ws;
    float* e2 = (float*)ws;                                              // 4 KiB
    unsigned long long* keys = (unsigned long long*)(ws + 4096);         // 2 MiB
    int* idx = (int*)(ws + 4096 + (size_t)SPLIT * N_ROWS * 8);           // 256 KiB

    hipMemsetAsync(loss, 0, sizeof(float), stream);
    e2_kernel<<<K_CODES / 256, 256, 0, stream>>>(emb, e2);
    dist_kernel<<<(N_ROWS / 256) * SPLIT, 256, 0, stream>>>(z, emb, e2, keys);
    combine_kernel<<<N_ROWS / 256, 256, 0, stream>>>(keys, idx);
    quant_kernel<<<OUT_ELEMS / 4 / 256, 256, 0, stream>>>(z, emb, idx, out, loss);
}

// Round 2
// 195.027 us; speedup vs baseline: 1.8435x; 1.8435x over previous
//
#include <hip/hip_runtime.h>
#include <stdint.h>

#define N_ROWS 65536
#define K_CODES 1024
#define D 64
#define OUT_ELEMS 4194304
#define LOSS_SCALE (1.25f / 4194304.0f)

typedef short short8 __attribute__((ext_vector_type(8)));
typedef float f32x4 __attribute__((ext_vector_type(4)));

__device__ __forceinline__ unsigned short f2bf(float f) {
    unsigned int u = __float_as_uint(f);
    return (unsigned short)((u + 0x7fffu + ((u >> 16) & 1u)) >> 16);  // RNE
}

// Prep: convert emb fp32 -> bf16 (row-major 1024x64) and compute ||e_k||^2.
#define ECH (K_CODES * D / 8)  // 8192 emb 8-elem chunks
__global__ __launch_bounds__(256) void prep_kernel(const float* __restrict__ emb,
                                                   unsigned short* __restrict__ eb,
                                                   float* __restrict__ e2) {
    int t = blockIdx.x * 256 + threadIdx.x;
    if (t < ECH) {
        const float4* s = (const float4*)emb;
        float4 a = s[2 * t], b = s[2 * t + 1];
        uint4 o;
        o.x = f2bf(a.x) | ((unsigned int)f2bf(a.y) << 16);
        o.y = f2bf(a.z) | ((unsigned int)f2bf(a.w) << 16);
        o.z = f2bf(b.x) | ((unsigned int)f2bf(b.y) << 16);
        o.w = f2bf(b.z) | ((unsigned int)f2bf(b.w) << 16);
        ((uint4*)eb)[t] = o;
    } else if (t < ECH + K_CODES) {
        int k = t - ECH;
        const float4* e4 = (const float4*)emb;
        float s = 0.f;
#pragma unroll
        for (int i = 0; i < 16; i++) {
            float4 v = e4[k * 16 + i];
            s += v.x * v.x + v.y * v.y + v.z * v.z + v.w * v.w;
        }
        e2[k] = s;
    }
}

// MFMA distance+argmin. Block = 64 z-rows (4 waves x 16 rows), all 1024 codes.
// A = emb codes (m = code-in-tile = lane&15 on load side), B = z rows (n = lane&15),
// D[row=quad*4+reg -> code][col=lane&15 -> z-row]. z-frags live in regs all kernel.
__global__ __launch_bounds__(256) void dist_kernel(const float* __restrict__ z,
                                                   const unsigned short* __restrict__ eb,
                                                   const float* __restrict__ e2,
                                                   int* __restrict__ idx) {
    const int wave = threadIdx.x >> 6;
    const int lane = threadIdx.x & 63;
    const int n = lane & 15;       // z-row within wave tile / B col
    const int q = lane >> 4;       // quad
    const int row_base = blockIdx.x * 64 + wave * 16;

    // B-frags: z[row_base+n][k], k-halves [0,32) and [32,64); lane k-base q*8.
    const float* zr = z + (size_t)(row_base + n) * D + q * 8;
    float4 f0 = *(const float4*)(zr);
    float4 f1 = *(const float4*)(zr + 4);
    float4 f2 = *(const float4*)(zr + 32);
    float4 f3 = *(const float4*)(zr + 36);
    short8 b0, b1;
    b0[0] = f2bf(f0.x); b0[1] = f2bf(f0.y); b0[2] = f2bf(f0.z); b0[3] = f2bf(f0.w);
    b0[4] = f2bf(f1.x); b0[5] = f2bf(f1.y); b0[6] = f2bf(f1.z); b0[7] = f2bf(f1.w);
    b1[0] = f2bf(f2.x); b1[1] = f2bf(f2.y); b1[2] = f2bf(f2.z); b1[3] = f2bf(f2.w);
    b1[4] = f2bf(f3.x); b1[5] = f2bf(f3.y); b1[6] = f2bf(f3.z); b1[7] = f2bf(f3.w);

    float bestd = INFINITY;
    int bestk = 0;

#pragma unroll 4
    for (int tile = 0; tile < K_CODES / 16; ++tile) {
        const unsigned short* er = eb + (size_t)(tile * 16 + n) * D + q * 8;
        short8 a0 = *(const short8*)(er);
        short8 a1 = *(const short8*)(er + 32);
        float4 ev = *(const float4*)(e2 + tile * 16 + q * 4);
        f32x4 acc = {0.f, 0.f, 0.f, 0.f};
        acc = __builtin_amdgcn_mfma_f32_16x16x32_bf16(a0, b0, acc, 0, 0, 0);
        acc = __builtin_amdgcn_mfma_f32_16x16x32_bf16(a1, b1, acc, 0, 0, 0);
        float e2r[4] = {ev.x, ev.y, ev.z, ev.w};
#pragma unroll
        for (int r = 0; r < 4; ++r) {
            float d = fmaf(-2.0f, acc[r], e2r[r]);
            if (d < bestd) { bestd = d; bestk = tile * 16 + q * 4 + r; }  // codes ascend -> first-min
        }
    }

    // Pack monotone key, min across the 4 quads (same z-row n).
    unsigned int db = __float_as_uint(bestd);
    db = (db & 0x80000000u) ? ~db : (db | 0x80000000u);
    unsigned long long key = ((unsigned long long)db << 32) | (unsigned int)bestk;
    unsigned long long o = __shfl_xor(key, 16, 64); key = o < key ? o : key;
    o = __shfl_xor(key, 32, 64); key = o < key ? o : key;
    if (q == 0) idx[row_base + n] = (int)(key & 0xFFFFFFFFu);
}

// Gather codebook rows (coalesced writes), accumulate 1.25 * mean((q - z)^2).
__global__ __launch_bounds__(256) void quant_kernel(const float* __restrict__ z,
                                                    const float* __restrict__ emb,
                                                    const int* __restrict__ idx,
                                                    float* __restrict__ out,
                                                    float* __restrict__ loss) {
    int i = blockIdx.x * 256 + threadIdx.x;  // float4 index
    int n = i >> 4;
    int d4 = i & 15;
    int k = idx[n];
    float4 qv = ((const float4*)emb)[k * 16 + d4];
    float4 zv = ((const float4*)z)[i];
    ((float4*)out)[i] = qv;
    float dx = qv.x - zv.x, dy = qv.y - zv.y, dz = qv.z - zv.z, dw = qv.w - zv.w;
    float ssum = dx * dx + dy * dy + dz * dz + dw * dw;
#pragma unroll
    for (int off = 32; off > 0; off >>= 1)
        ssum += __shfl_down(ssum, off, 64);
    __shared__ float ps[4];
    int wave = threadIdx.x >> 6;
    int lane = threadIdx.x & 63;
    if (lane == 0) ps[wave] = ssum;
    __syncthreads();
    if (threadIdx.x == 0) {
        float bs = ps[0] + ps[1] + ps[2] + ps[3];
        atomicAdd(loss, bs * LOSS_SCALE);
    }
}

extern "C" void kernel_launch(void* const* d_in, const int* in_sizes, int n_in,
                              void* d_out, int out_size, void* d_ws, size_t ws_size,
                              hipStream_t stream) {
    const float* z = (const float*)d_in[0];
    const float* emb = (const float*)d_in[1];
    float* out = (float*)d_out;
    float* loss = out + OUT_ELEMS;

    char* ws = (char*)d_ws;
    float* e2 = (float*)ws;                                   // 4 KiB
    unsigned short* eb = (unsigned short*)(ws + 4096);        // 128 KiB bf16 codebook
    int* idx = (int*)(ws + 4096 + K_CODES * D * 2);           // 256 KiB

    hipMemsetAsync(loss, 0, sizeof(float), stream);
    prep_kernel<<<(ECH + K_CODES + 255) / 256, 256, 0, stream>>>(emb, eb, e2);
    dist_kernel<<<N_ROWS / 64, 256, 0, stream>>>(z, eb, e2, idx);
    quant_kernel<<<OUT_ELEMS / 4 / 256, 256, 0, stream>>>(z, emb, idx, out, loss);
}

// Round 3
// 109.848 us; speedup vs baseline: 3.2731x; 1.7754x over previous
//
#include <hip/hip_runtime.h>
#include <stdint.h>

#define N_ROWS 65536
#define K_CODES 1024
#define D 64
#define OUT_ELEMS 4194304
#define LOSS_SCALE (1.25f / 4194304.0f)
#define ROWS_PER_BLOCK 128
#define GRID_DIST (N_ROWS / ROWS_PER_BLOCK)  // 512

typedef short short8 __attribute__((ext_vector_type(8)));
typedef float f32x4 __attribute__((ext_vector_type(4)));

__device__ __forceinline__ unsigned short f2bf(float f) {
    unsigned int u = __float_as_uint(f);
    return (unsigned short)((u + 0x7fffu + ((u >> 16) & 1u)) >> 16);  // RNE
}

// Prep: ebm2 = bf16(-2*emb) (so MFMA acc = e2 - 2*z.e directly); e2 = ||e_k||^2 (fp32-exact).
#define ECH (K_CODES * D / 8)  // 8192
__global__ __launch_bounds__(256) void prep_kernel(const float* __restrict__ emb,
                                                   unsigned short* __restrict__ ebm2,
                                                   float* __restrict__ e2) {
    int t = blockIdx.x * 256 + threadIdx.x;
    if (t < ECH) {
        const float4* s = (const float4*)emb;
        float4 a = s[2 * t], b = s[2 * t + 1];
        uint4 o;
        o.x = f2bf(-2.f * a.x) | ((unsigned int)f2bf(-2.f * a.y) << 16);
        o.y = f2bf(-2.f * a.z) | ((unsigned int)f2bf(-2.f * a.w) << 16);
        o.z = f2bf(-2.f * b.x) | ((unsigned int)f2bf(-2.f * b.y) << 16);
        o.w = f2bf(-2.f * b.z) | ((unsigned int)f2bf(-2.f * b.w) << 16);
        ((uint4*)ebm2)[t] = o;
    } else if (t < ECH + K_CODES) {
        int k = t - ECH;
        const float4* e4 = (const float4*)emb;
        float s = 0.f;
#pragma unroll
        for (int i = 0; i < 16; i++) {
            float4 v = e4[k * 16 + i];
            s += v.x * v.x + v.y * v.y + v.z * v.z + v.w * v.w;
        }
        e2[k] = s;
    }
}

// Fused: MFMA distances (argmin) + quantized gather-write + loss partial.
// Block = 4 waves x 32 rows = 128 z-rows; all 1024 codes per wave; prefetch dist 2.
__global__ __launch_bounds__(256) void dist_fused_kernel(
        const float* __restrict__ z, const unsigned short* __restrict__ ebm2,
        const float* __restrict__ e2, const float* __restrict__ emb,
        float* __restrict__ out, float* __restrict__ partials) {
    const int tid = threadIdx.x;
    const int wave = tid >> 6, lane = tid & 63;
    const int n = lane & 15, q = lane >> 4;
    const int block_row0 = blockIdx.x * ROWS_PER_BLOCK;

    // B-frags: 2 row-sets of 16 z-rows, bf16, k-halves [0,32),[32,64), lane k-base q*8.
    short8 b[2][2];
#pragma unroll
    for (int rs = 0; rs < 2; rs++) {
        const float* zr = z + (size_t)(block_row0 + wave * 32 + rs * 16 + n) * D + q * 8;
        float4 f0 = *(const float4*)(zr);
        float4 f1 = *(const float4*)(zr + 4);
        float4 f2 = *(const float4*)(zr + 32);
        float4 f3 = *(const float4*)(zr + 36);
        short8 lo, hi;
        lo[0] = f2bf(f0.x); lo[1] = f2bf(f0.y); lo[2] = f2bf(f0.z); lo[3] = f2bf(f0.w);
        lo[4] = f2bf(f1.x); lo[5] = f2bf(f1.y); lo[6] = f2bf(f1.z); lo[7] = f2bf(f1.w);
        hi[0] = f2bf(f2.x); hi[1] = f2bf(f2.y); hi[2] = f2bf(f2.z); hi[3] = f2bf(f2.w);
        hi[4] = f2bf(f3.x); hi[5] = f2bf(f3.y); hi[6] = f2bf(f3.z); hi[7] = f2bf(f3.w);
        b[rs][0] = lo; b[rs][1] = hi;
    }

    float bestd[2] = {INFINITY, INFINITY};
    int bestk[2] = {0, 0};

    // Two named prefetch slots (no arrays -> no scratch), distance 2.
    short8 A0a, A1a, A0b, A1b;
    f32x4 Ea, Eb;
    {
        const unsigned short* er0 = ebm2 + (size_t)n * D + q * 8;
        A0a = *(const short8*)er0; A1a = *(const short8*)(er0 + 32);
        Ea = *(const f32x4*)(e2 + q * 4);
        const unsigned short* er1 = ebm2 + (size_t)(16 + n) * D + q * 8;
        A0b = *(const short8*)er1; A1b = *(const short8*)(er1 + 32);
        Eb = *(const f32x4*)(e2 + 16 + q * 4);
    }

    auto step = [&](int t, short8& A0, short8& A1, f32x4& E) {
        f32x4 acc0 = E, acc1 = E;  // acc init = ||e||^2
        acc0 = __builtin_amdgcn_mfma_f32_16x16x32_bf16(A0, b[0][0], acc0, 0, 0, 0);
        acc0 = __builtin_amdgcn_mfma_f32_16x16x32_bf16(A1, b[0][1], acc0, 0, 0, 0);
        acc1 = __builtin_amdgcn_mfma_f32_16x16x32_bf16(A0, b[1][0], acc1, 0, 0, 0);
        acc1 = __builtin_amdgcn_mfma_f32_16x16x32_bf16(A1, b[1][1], acc1, 0, 0, 0);
        // prefetch tile t+2 into this slot (clamped; harmless re-read at loop end)
        int tp = (t + 2 > 63) ? 63 : (t + 2);
        const unsigned short* er = ebm2 + (size_t)(tp * 16 + n) * D + q * 8;
        A0 = *(const short8*)er;
        A1 = *(const short8*)(er + 32);
        E = *(const f32x4*)(e2 + tp * 16 + q * 4);
#pragma unroll
        for (int r = 0; r < 4; r++) {  // codes ascend in (t, r) per lane -> strict < = first-min
            float d0 = acc0[r];
            if (d0 < bestd[0]) { bestd[0] = d0; bestk[0] = t * 16 + q * 4 + r; }
            float d1 = acc1[r];
            if (d1 < bestd[1]) { bestd[1] = d1; bestk[1] = t * 16 + q * 4 + r; }
        }
    };

    for (int t = 0; t < 64; t += 2) {
        step(t, A0a, A1a, Ea);
        step(t + 1, A0b, A1b, Eb);
    }

    // Argmin across quads (u64 key: monotone dist | index -> numpy tie semantics).
    __shared__ int sh_idx[ROWS_PER_BLOCK];
#pragma unroll
    for (int rs = 0; rs < 2; rs++) {
        unsigned int db = __float_as_uint(bestd[rs]);
        db = (db & 0x80000000u) ? ~db : (db | 0x80000000u);
        unsigned long long key = ((unsigned long long)db << 32) | (unsigned int)bestk[rs];
        unsigned long long o = __shfl_xor(key, 16, 64); key = o < key ? o : key;
        o = __shfl_xor(key, 32, 64); key = o < key ? o : key;
        if (q == 0) sh_idx[wave * 32 + rs * 16 + n] = (int)(key & 0xFFFFFFFFu);
    }
    __syncthreads();

    // Epilogue: coalesced gather+write of quantized, fp32 loss partial.
    float ssum = 0.f;
    const float4* z4 = (const float4*)z;
    float4* o4 = (float4*)out;
#pragma unroll
    for (int it = 0; it < 8; it++) {
        int c = it * 256 + tid;            // [0, 2048) float4 chunks of this block
        int lrow = c >> 4, d4 = c & 15;
        int k = sh_idx[lrow];
        size_t gi = (size_t)block_row0 * 16 + c;
        float4 qv = ((const float4*)emb)[k * 16 + d4];
        float4 zv = z4[gi];
        o4[gi] = qv;
        float dx = qv.x - zv.x, dy = qv.y - zv.y, dz = qv.z - zv.z, dw = qv.w - zv.w;
        ssum += dx * dx + dy * dy + dz * dz + dw * dw;
    }
#pragma unroll
    for (int off = 32; off > 0; off >>= 1)
        ssum += __shfl_down(ssum, off, 64);
    __shared__ float ps[4];
    if (lane == 0) ps[wave] = ssum;
    __syncthreads();
    if (tid == 0) partials[blockIdx.x] = ps[0] + ps[1] + ps[2] + ps[3];
}

// Single block: sum 512 partials -> loss (no atomics anywhere).
__global__ __launch_bounds__(256) void loss_kernel(const float* __restrict__ partials,
                                                   float* __restrict__ loss) {
    float s = partials[threadIdx.x] + partials[threadIdx.x + 256];
#pragma unroll
    for (int off = 32; off > 0; off >>= 1)
        s += __shfl_down(s, off, 64);
    __shared__ float ps[4];
    int wave = threadIdx.x >> 6, lane = threadIdx.x & 63;
    if (lane == 0) ps[wave] = s;
    __syncthreads();
    if (threadIdx.x == 0) loss[0] = (ps[0] + ps[1] + ps[2] + ps[3]) * LOSS_SCALE;
}

extern "C" void kernel_launch(void* const* d_in, const int* in_sizes, int n_in,
                              void* d_out, int out_size, void* d_ws, size_t ws_size,
                              hipStream_t stream) {
    const float* z = (const float*)d_in[0];
    const float* emb = (const float*)d_in[1];
    float* out = (float*)d_out;
    float* loss = out + OUT_ELEMS;

    char* ws = (char*)d_ws;
    float* e2 = (float*)ws;                                       // 4 KiB
    unsigned short* ebm2 = (unsigned short*)(ws + 4096);          // 128 KiB
    float* partials = (float*)(ws + 4096 + 131072 + 8192);        // 2 KiB (8K pad)

    prep_kernel<<<(ECH + K_CODES + 255) / 256, 256, 0, stream>>>(emb, ebm2, e2);
    dist_fused_kernel<<<GRID_DIST, 256, 0, stream>>>(z, ebm2, e2, emb, out, partials);
    loss_kernel<<<1, 256, 0, stream>>>(partials, loss);
}

// Round 4
// 90.525 us; speedup vs baseline: 3.9717x; 1.2135x over previous
//
#include <hip/hip_runtime.h>
#include <stdint.h>

#define N_ROWS 65536
#define K_CODES 1024
#define D 64
#define OUT_ELEMS 4194304
#define LOSS_SCALE (1.25f / 4194304.0f)
#define ROWS_PER_BLOCK 128
#define GRID_DIST (N_ROWS / ROWS_PER_BLOCK)  // 512

typedef short short8 __attribute__((ext_vector_type(8)));
typedef float f32x4 __attribute__((ext_vector_type(4)));

__device__ __forceinline__ unsigned short f2bf(float f) {
    unsigned int u = __float_as_uint(f);
    return (unsigned short)((u + 0x7fffu + ((u >> 16) & 1u)) >> 16);  // RNE
}

#define GLOAD_LDS16(g, l)                                                          \
    __builtin_amdgcn_global_load_lds((const __attribute__((address_space(1))) void*)(g), \
                                     (__attribute__((address_space(3))) void*)(l), 16, 0, 0)

// Prep: ebm2 = bf16(-2*emb) (so MFMA acc = e2 - 2*z.e directly); e2 = ||e_k||^2 (fp32-exact).
#define ECH (K_CODES * D / 8)  // 8192
__global__ __launch_bounds__(256) void prep_kernel(const float* __restrict__ emb,
                                                   unsigned short* __restrict__ ebm2,
                                                   float* __restrict__ e2) {
    int t = blockIdx.x * 256 + threadIdx.x;
    if (t < ECH) {
        const float4* s = (const float4*)emb;
        float4 a = s[2 * t], b = s[2 * t + 1];
        uint4 o;
        o.x = f2bf(-2.f * a.x) | ((unsigned int)f2bf(-2.f * a.y) << 16);
        o.y = f2bf(-2.f * a.z) | ((unsigned int)f2bf(-2.f * a.w) << 16);
        o.z = f2bf(-2.f * b.x) | ((unsigned int)f2bf(-2.f * b.y) << 16);
        o.w = f2bf(-2.f * b.z) | ((unsigned int)f2bf(-2.f * b.w) << 16);
        ((uint4*)ebm2)[t] = o;
    } else if (t < ECH + K_CODES) {
        int k = t - ECH;
        const float4* e4 = (const float4*)emb;
        float s = 0.f;
#pragma unroll
        for (int i = 0; i < 16; i++) {
            float4 v = e4[k * 16 + i];
            s += v.x * v.x + v.y * v.y + v.z * v.z + v.w * v.w;
        }
        e2[k] = s;
    }
}

// Fused MFMA distance+argmin+quantize+loss.
// Codebook (bf16, pre-scaled by -2) staged to LDS in 4 chunks of 256 codes,
// double-buffered 2x32KB via async global_load_lds, XOR-swizzled so the
// ds_read_b128 A-frag reads are 2-way (free) instead of 16-way conflicted.
__global__ __launch_bounds__(256, 2) void dist_fused_kernel(
        const float* __restrict__ z, const unsigned short* __restrict__ ebm2,
        const float* __restrict__ e2, const float* __restrict__ emb,
        float* __restrict__ out, float* __restrict__ partials) {
    __shared__ __align__(16) char smem[65536];  // 2x32KB chunk buffers; re-used by epilogue
    const int tid = threadIdx.x;
    const int wave = tid >> 6, lane = tid & 63;
    const int n = lane & 15, q = lane >> 4, nb = n & 7;
    const int block_row0 = blockIdx.x * ROWS_PER_BLOCK;

    // B-frags: 2 row-sets of 16 z-rows each, bf16, k-halves [0,32),[32,64).
    short8 b[2][2];
#pragma unroll
    for (int rs = 0; rs < 2; rs++) {
        const float* zr = z + (size_t)(block_row0 + wave * 32 + rs * 16 + n) * D + q * 8;
        float4 f0 = *(const float4*)(zr);
        float4 f1 = *(const float4*)(zr + 4);
        float4 f2 = *(const float4*)(zr + 32);
        float4 f3 = *(const float4*)(zr + 36);
        short8 lo, hi;
        lo[0] = f2bf(f0.x); lo[1] = f2bf(f0.y); lo[2] = f2bf(f0.z); lo[3] = f2bf(f0.w);
        lo[4] = f2bf(f1.x); lo[5] = f2bf(f1.y); lo[6] = f2bf(f1.z); lo[7] = f2bf(f1.w);
        hi[0] = f2bf(f2.x); hi[1] = f2bf(f2.y); hi[2] = f2bf(f2.z); hi[3] = f2bf(f2.w);
        hi[4] = f2bf(f3.x); hi[5] = f2bf(f3.y); hi[6] = f2bf(f3.z); hi[7] = f2bf(f3.w);
        b[rs][0] = lo; b[rs][1] = hi;
    }

    // Stage one 256-code chunk (2048 16B-slots) into buf[c&1]. Slot S holds
    // logical unit u_log = (S&7) ^ (code&7) of code S>>3 -> swizzled source fetch.
    auto stage = [&](int c) {
        const int bufoff = (c & 1) << 15;
        const uint4* gsrc = (const uint4*)ebm2;
#pragma unroll
        for (int r = 0; r < 8; r++) {
            int S = c * 2048 + r * 256 + tid;                       // global slot
            int P = (S & ~7) | ((S & 7) ^ ((S >> 3) & 7));          // swizzled source
            char* l = smem + bufoff + (r * 256 + (tid & ~63)) * 16; // wave-uniform base
            GLOAD_LDS16(gsrc + P, l);
        }
    };

    // e2 prefetch slots (global, depth 2) + per-lane swizzled LDS read offsets.
    f32x4 Ea = *(const f32x4*)(e2 + q * 4);
    f32x4 Eb = *(const f32x4*)(e2 + 16 + q * 4);
    const int base0 = n * 128 + ((q ^ nb) << 4);
    const int base1 = n * 128 + (((4 | q) ^ nb) << 4);

    float bestd[2] = {INFINITY, INFINITY};
    int bestk[2] = {0, 0};

    stage(0);
    __syncthreads();  // drains staging vmcnt
    for (int c = 0; c < 4; c++) {
        if (c < 3) stage(c + 1);  // async into other buffer, overlaps compute
        const char* buf = smem + ((c & 1) << 15);
#pragma unroll
        for (int tl = 0; tl < 16; tl++) {
            const int t = c * 16 + tl;
            short8 a0 = *(const short8*)(buf + tl * 2048 + base0);
            short8 a1 = *(const short8*)(buf + tl * 2048 + base1);
            f32x4 E = (tl & 1) ? Eb : Ea;
            f32x4 acc0 = E, acc1 = E;  // acc init = ||e||^2
            acc0 = __builtin_amdgcn_mfma_f32_16x16x32_bf16(a0, b[0][0], acc0, 0, 0, 0);
            acc0 = __builtin_amdgcn_mfma_f32_16x16x32_bf16(a1, b[0][1], acc0, 0, 0, 0);
            acc1 = __builtin_amdgcn_mfma_f32_16x16x32_bf16(a0, b[1][0], acc1, 0, 0, 0);
            acc1 = __builtin_amdgcn_mfma_f32_16x16x32_bf16(a1, b[1][1], acc1, 0, 0, 0);
            int tp = (t + 2 > 63) ? 63 : (t + 2);
            f32x4 En = *(const f32x4*)(e2 + tp * 16 + q * 4);
            if (tl & 1) Eb = En; else Ea = En;
#pragma unroll
            for (int r = 0; r < 4; r++) {  // per-lane codes ascend in (t,r): strict < = first-min
                float d0 = acc0[r];
                if (d0 < bestd[0]) { bestd[0] = d0; bestk[0] = t * 16 + q * 4 + r; }
                float d1 = acc1[r];
                if (d1 < bestd[1]) { bestd[1] = d1; bestk[1] = t * 16 + q * 4 + r; }
            }
        }
        __syncthreads();  // chunk c reads done; also drains stage(c+1)
    }

    // Cross-quad argmin (u64 key: monotone dist | index -> numpy tie semantics).
    int* sh_idx = (int*)smem;            // staging buffers no longer needed
    float* ps = (float*)(smem + 512);
#pragma unroll
    for (int rs = 0; rs < 2; rs++) {
        unsigned int db = __float_as_uint(bestd[rs]);
        db = (db & 0x80000000u) ? ~db : (db | 0x80000000u);
        unsigned long long key = ((unsigned long long)db << 32) | (unsigned int)bestk[rs];
        unsigned long long o = __shfl_xor(key, 16, 64); key = o < key ? o : key;
        o = __shfl_xor(key, 32, 64); key = o < key ? o : key;
        if (q == 0) sh_idx[wave * 32 + rs * 16 + n] = (int)(key & 0xFFFFFFFFu);
    }
    __syncthreads();

    // Epilogue: coalesced gather+write of quantized, fp32 loss partial.
    float ssum = 0.f;
    const float4* z4 = (const float4*)z;
    float4* o4 = (float4*)out;
#pragma unroll
    for (int it = 0; it < 8; it++) {
        int cidx = it * 256 + tid;  // [0, 2048) float4 chunks of this block
        int lrow = cidx >> 4, d4 = cidx & 15;
        int k = sh_idx[lrow];
        size_t gi = (size_t)block_row0 * 16 + cidx;
        float4 qv = ((const float4*)emb)[k * 16 + d4];
        float4 zv = z4[gi];
        o4[gi] = qv;
        float dx = qv.x - zv.x, dy = qv.y - zv.y, dz = qv.z - zv.z, dw = qv.w - zv.w;
        ssum += dx * dx + dy * dy + dz * dz + dw * dw;
    }
#pragma unroll
    for (int off = 32; off > 0; off >>= 1)
        ssum += __shfl_down(ssum, off, 64);
    if (lane == 0) ps[wave] = ssum;
    __syncthreads();
    if (tid == 0) partials[blockIdx.x] = ps[0] + ps[1] + ps[2] + ps[3];
}

// Single block: sum 512 partials -> loss (no atomics anywhere).
__global__ __launch_bounds__(256) void loss_kernel(const float* __restrict__ partials,
                                                   float* __restrict__ loss) {
    float s = partials[threadIdx.x] + partials[threadIdx.x + 256];
#pragma unroll
    for (int off = 32; off > 0; off >>= 1)
        s += __shfl_down(s, off, 64);
    __shared__ float ps[4];
    int wave = threadIdx.x >> 6, lane = threadIdx.x & 63;
    if (lane == 0) ps[wave] = s;
    __syncthreads();
    if (threadIdx.x == 0) loss[0] = (ps[0] + ps[1] + ps[2] + ps[3]) * LOSS_SCALE;
}

extern "C" void kernel_launch(void* const* d_in, const int* in_sizes, int n_in,
                              void* d_out, int out_size, void* d_ws, size_t ws_size,
                              hipStream_t stream) {
    const float* z = (const float*)d_in[0];
    const float* emb = (const float*)d_in[1];
    float* out = (float*)d_out;
    float* loss = out + OUT_ELEMS;

    char* ws = (char*)d_ws;
    float* e2 = (float*)ws;                                       // 4 KiB
    unsigned short* ebm2 = (unsigned short*)(ws + 4096);          // 128 KiB
    float* partials = (float*)(ws + 4096 + 131072 + 8192);        // 2 KiB (8K pad)

    prep_kernel<<<(ECH + K_CODES + 255) / 256, 256, 0, stream>>>(emb, ebm2, e2);
    dist_fused_kernel<<<GRID_DIST, 256, 0, stream>>>(z, ebm2, e2, emb, out, partials);
    loss_kernel<<<1, 256, 0, stream>>>(partials, loss);
}